// Round 1
// baseline (2036.479 us; speedup 1.0000x reference)
//
#include <hip/hip_runtime.h>
#include <math.h>

#define NHID 64

// ---------------------------------------------------------------------------
// K1: per-node degree histogram (int atomics, random over 400KB -> L2)
// ---------------------------------------------------------------------------
__global__ __launch_bounds__(256) void k_hist(const int* __restrict__ src,
                                              const int* __restrict__ dst,
                                              int* __restrict__ cnt_src,
                                              int* __restrict__ cnt_dst, int E) {
    int stride = gridDim.x * blockDim.x;
    for (int e = blockIdx.x * blockDim.x + threadIdx.x; e < E; e += stride) {
        atomicAdd(&cnt_src[src[e]], 1);
        atomicAdd(&cnt_dst[dst[e]], 1);
    }
}

// ---------------------------------------------------------------------------
// K2: exclusive scan of both count arrays (one workgroup per array; N=100K so
// ~98 chunk iterations of a 1024-wide Hillis-Steele scan — microseconds)
// ---------------------------------------------------------------------------
__global__ __launch_bounds__(1024) void k_scan(const int* __restrict__ cnt0, int* __restrict__ off0, int* __restrict__ cur0,
                                               const int* __restrict__ cnt1, int* __restrict__ off1, int* __restrict__ cur1,
                                               int N) {
    const int* cnt = blockIdx.x ? cnt1 : cnt0;
    int* off = blockIdx.x ? off1 : off0;
    int* cur = blockIdx.x ? cur1 : cur0;
    __shared__ int sdata[1024];
    int tid = threadIdx.x;
    int running = 0;
    for (int base = 0; base < N; base += 1024) {
        int i = base + tid;
        int v = (i < N) ? cnt[i] : 0;
        sdata[tid] = v;
        __syncthreads();
        for (int o = 1; o < 1024; o <<= 1) {
            int t = (tid >= o) ? sdata[tid - o] : 0;
            __syncthreads();
            sdata[tid] += t;
            __syncthreads();
        }
        int excl = sdata[tid] - v;   // exclusive within chunk
        if (i < N) { off[i] = running + excl; cur[i] = running + excl; }
        running += sdata[1023];
        __syncthreads();
    }
    if (tid == 0) off[N] = running;
}

// ---------------------------------------------------------------------------
// K3: CSR fill. csr_dst[slot of dst-segment] = src endpoint (for agg);
//     csr_src[slot of src-segment] = dst endpoint (for final scatter-mean).
// ---------------------------------------------------------------------------
__global__ __launch_bounds__(256) void k_fill(const int* __restrict__ src,
                                              const int* __restrict__ dst,
                                              int* __restrict__ cur_src, int* __restrict__ cur_dst,
                                              int* __restrict__ csr_src, int* __restrict__ csr_dst, int E) {
    int stride = gridDim.x * blockDim.x;
    for (int e = blockIdx.x * blockDim.x + threadIdx.x; e += 0, e < E; e += stride) {
        int s = src[e], d = dst[e];
        int p = atomicAdd(&cur_dst[d], 1);
        csr_dst[p] = s;
        int q = atomicAdd(&cur_src[s], 1);
        csr_src[q] = d;
    }
}

// ---------------------------------------------------------------------------
// K4: agg[n,:] = mean over in-edges of X[src,:]. Wave-per-node: lane t owns
// feature t; edge indices loaded 64-wide then shfl-broadcast; each edge is one
// coalesced 256B row read (X = 25.6MB, L2/L3 resident).
// ---------------------------------------------------------------------------
__global__ __launch_bounds__(256) void k_agg(const float* __restrict__ X,
                                             const int* __restrict__ off_dst,
                                             const int* __restrict__ csr_dst,
                                             float* __restrict__ agg, int N) {
    int lane = threadIdx.x & 63;
    int node = blockIdx.x * 4 + (threadIdx.x >> 6);
    if (node >= N) return;
    int s0 = off_dst[node], s1 = off_dst[node + 1];
    float acc = 0.f;
    for (int base = s0; base < s1; base += 64) {
        int idx = (base + lane < s1) ? csr_dst[base + lane] : 0;
        int cnt = min(64, s1 - base);
        for (int j = 0; j < cnt; ++j) {
            int m = __shfl(idx, j);
            acc += X[(size_t)m * NHID + lane];   // independent loads -> MLP
        }
    }
    int deg = s1 - s0;
    agg[(size_t)node * NHID + lane] = acc / (float)max(deg, 1);
}

// ---------------------------------------------------------------------------
// K5: fused per-node GEMMs. X2 = relu(X·Wself + agg·Wneigh + b) is computed in
// registers and immediately consumed: a = X2·A + Qb, b = X2·B, where A/B are
// the top/bottom halves of Qw reshaped so column c = h*16+d. All four 64x64
// matrices staged once per block in 64KB LDS; 512 blocks grid-stride nodes.
// ---------------------------------------------------------------------------
__global__ __launch_bounds__(256, 2) void k_node_gemm(const float* __restrict__ X,
                                                      const float* __restrict__ agg,
                                                      const float* __restrict__ Wself,
                                                      const float* __restrict__ Wneigh,
                                                      const float* __restrict__ bconv,
                                                      const float* __restrict__ Qw,
                                                      const float* __restrict__ Qb,
                                                      float* __restrict__ aOut,
                                                      float* __restrict__ bOut, int N) {
    __shared__ float sWs[4096];
    __shared__ float sWn[4096];
    __shared__ float sA[4096];
    __shared__ float sB[4096];
    for (int i = threadIdx.x; i < 4096; i += 256) {
        sWs[i] = Wself[i];
        sWn[i] = Wneigh[i];
        int f = i >> 6, c = i & 63, h = c >> 4, d = c & 15;
        sA[i] = Qw[h * 2048 + f * 16 + d];          // Qw[h, f, d],     f in [0,64)
        sB[i] = Qw[h * 2048 + (f + 64) * 16 + d];   // Qw[h, 64+f, d]
    }
    __syncthreads();
    int lane = threadIdx.x & 63, wid = threadIdx.x >> 6;
    float bc = bconv[lane];
    float qb = Qb[lane];  // Qb flat index h*16+d == lane
    for (int n = blockIdx.x * 4 + wid; n < N; n += gridDim.x * 4) {
        float x = X[(size_t)n * NHID + lane];
        float g = agg[(size_t)n * NHID + lane];
        float acc = bc;
        #pragma unroll
        for (int f = 0; f < 64; ++f) {
            float xf = __shfl(x, f);
            float gf = __shfl(g, f);
            acc += xf * sWs[f * 64 + lane] + gf * sWn[f * 64 + lane];
        }
        float x2 = fmaxf(acc, 0.f);
        float accA = qb, accB = 0.f;
        #pragma unroll
        for (int f = 0; f < 64; ++f) {
            float xf = __shfl(x2, f);
            accA += xf * sA[f * 64 + lane];
            accB += xf * sB[f * 64 + lane];
        }
        aOut[(size_t)n * NHID + lane] = accA;
        bOut[(size_t)n * NHID + lane] = accB;
    }
}

// ---------------------------------------------------------------------------
// K6: gg[n,:] = tanh(mean over out-edges of (a[n,:] + b[dst,:])^2)
// Same wave-per-node gather pattern as K4.
// ---------------------------------------------------------------------------
__global__ __launch_bounds__(256) void k_final(const float* __restrict__ aF,
                                               const float* __restrict__ bF,
                                               const int* __restrict__ off_src,
                                               const int* __restrict__ csr_src,
                                               float* __restrict__ out, int N) {
    int lane = threadIdx.x & 63;
    int node = blockIdx.x * 4 + (threadIdx.x >> 6);
    if (node >= N) return;
    int s0 = off_src[node], s1 = off_src[node + 1];
    float av = aF[(size_t)node * NHID + lane];
    float acc = 0.f;
    for (int base = s0; base < s1; base += 64) {
        int idx = (base + lane < s1) ? csr_src[base + lane] : 0;
        int cnt = min(64, s1 - base);
        for (int j = 0; j < cnt; ++j) {
            int m = __shfl(idx, j);
            float t = av + bF[(size_t)m * NHID + lane];
            acc += t * t;   // P = 2.0 -> |.|^2 == square
        }
    }
    int deg = s1 - s0;
    out[(size_t)node * NHID + lane] = tanhf(acc / (float)max(deg, 1));
}

// ---------------------------------------------------------------------------
extern "C" void kernel_launch(void* const* d_in, const int* in_sizes, int n_in,
                              void* d_out, int out_size, void* d_ws, size_t ws_size,
                              hipStream_t stream) {
    const float* X      = (const float*)d_in[0];
    const int*   ei     = (const int*)d_in[1];
    const float* Wself  = (const float*)d_in[2];
    const float* Wneigh = (const float*)d_in[3];
    const float* bconv  = (const float*)d_in[4];
    const float* Qw     = (const float*)d_in[5];
    const float* Qb     = (const float*)d_in[6];

    int N = in_sizes[0] / NHID;
    int E = in_sizes[1] / 2;
    const int* src = ei;        // edge_index[0]
    const int* dst = ei + E;    // edge_index[1]

    // workspace carve-out (~105 MB total)
    char* ws = (char*)d_ws;
    size_t pos = 0;
    auto alloc = [&](size_t bytes) -> void* {
        pos = (pos + 255) & ~(size_t)255;
        void* p = ws + pos;
        pos += bytes;
        return p;
    };
    float* aggF    = (float*)alloc((size_t)N * NHID * 4);
    float* aF      = (float*)alloc((size_t)N * NHID * 4);
    float* bF      = (float*)alloc((size_t)N * NHID * 4);
    int*   csr_dst = (int*)alloc((size_t)E * 4);
    int*   csr_src = (int*)alloc((size_t)E * 4);
    int*   cnt     = (int*)alloc((size_t)2 * N * 4);   // [cnt_dst | cnt_src]
    int*   cnt_dst = cnt;
    int*   cnt_src = cnt + N;
    int*   off_dst = (int*)alloc((size_t)(N + 1) * 4);
    int*   off_src = (int*)alloc((size_t)(N + 1) * 4);
    int*   cur_dst = (int*)alloc((size_t)N * 4);
    int*   cur_src = (int*)alloc((size_t)N * 4);
    (void)ws_size; (void)n_in; (void)out_size;

    hipMemsetAsync(cnt, 0, (size_t)2 * N * 4, stream);

    k_hist<<<4096, 256, 0, stream>>>(src, dst, cnt_src, cnt_dst, E);
    k_scan<<<2, 1024, 0, stream>>>(cnt_dst, off_dst, cur_dst,
                                   cnt_src, off_src, cur_src, N);
    k_fill<<<4096, 256, 0, stream>>>(src, dst, cur_src, cur_dst, csr_src, csr_dst, E);
    k_agg<<<(N + 3) / 4, 256, 0, stream>>>(X, off_dst, csr_dst, aggF, N);
    k_node_gemm<<<512, 256, 0, stream>>>(X, aggF, Wself, Wneigh, bconv, Qw, Qb, aF, bF, N);
    k_final<<<(N + 3) / 4, 256, 0, stream>>>(aF, bF, off_src, csr_src, (float*)d_out, N);
}

// Round 2
// 1505.773 us; speedup vs baseline: 1.3524x; 1.3524x over previous
//
#include <hip/hip_runtime.h>
#include <math.h>

#define NHID 64

// ---------------------------------------------------------------------------
// K1: per-node degree histogram (int atomics, random over 800KB -> L2)
// ---------------------------------------------------------------------------
__global__ __launch_bounds__(256) void k_hist(const int* __restrict__ src,
                                              const int* __restrict__ dst,
                                              int* __restrict__ cnt_src,
                                              int* __restrict__ cnt_dst, int E) {
    int stride = gridDim.x * blockDim.x;
    for (int e = blockIdx.x * blockDim.x + threadIdx.x; e < E; e += stride) {
        atomicAdd(&cnt_src[src[e]], 1);
        atomicAdd(&cnt_dst[dst[e]], 1);
    }
}

// ---------------------------------------------------------------------------
// K2: exclusive scan of both count arrays (one workgroup per array)
// ---------------------------------------------------------------------------
__global__ __launch_bounds__(1024) void k_scan(const int* __restrict__ cnt0, int* __restrict__ off0, int* __restrict__ cur0,
                                               const int* __restrict__ cnt1, int* __restrict__ off1, int* __restrict__ cur1,
                                               int N) {
    const int* cnt = blockIdx.x ? cnt1 : cnt0;
    int* off = blockIdx.x ? off1 : off0;
    int* cur = blockIdx.x ? cur1 : cur0;
    __shared__ int sdata[1024];
    int tid = threadIdx.x;
    int running = 0;
    for (int base = 0; base < N; base += 1024) {
        int i = base + tid;
        int v = (i < N) ? cnt[i] : 0;
        sdata[tid] = v;
        __syncthreads();
        for (int o = 1; o < 1024; o <<= 1) {
            int t = (tid >= o) ? sdata[tid - o] : 0;
            __syncthreads();
            sdata[tid] += t;
            __syncthreads();
        }
        int excl = sdata[tid] - v;   // exclusive within chunk
        if (i < N) { off[i] = running + excl; cur[i] = running + excl; }
        running += sdata[1023];
        __syncthreads();
    }
    if (tid == 0) off[N] = running;
}

// ---------------------------------------------------------------------------
// K3: CSR fill. csr_dst[slot of dst-segment] = src endpoint (for agg);
//     csr_src[slot of src-segment] = dst endpoint (for final scatter-mean).
// ---------------------------------------------------------------------------
__global__ __launch_bounds__(256) void k_fill(const int* __restrict__ src,
                                              const int* __restrict__ dst,
                                              int* __restrict__ cur_src, int* __restrict__ cur_dst,
                                              int* __restrict__ csr_src, int* __restrict__ csr_dst, int E) {
    int stride = gridDim.x * blockDim.x;
    for (int e = blockIdx.x * blockDim.x + threadIdx.x; e < E; e += stride) {
        int s = src[e], d = dst[e];
        int p = atomicAdd(&cur_dst[d], 1);
        csr_dst[p] = s;
        int q = atomicAdd(&cur_src[s], 1);
        csr_src[q] = d;
    }
}

// ---------------------------------------------------------------------------
// K4: agg[n,:] = mean over in-edges of X[src,:]. Wave-per-node: lane t owns
// feature t; edge indices loaded 64-wide then shfl-broadcast; each edge is one
// coalesced 256B row read (X = 25.6MB, L2/L3 resident).
// ---------------------------------------------------------------------------
__global__ __launch_bounds__(256) void k_agg(const float* __restrict__ X,
                                             const int* __restrict__ off_dst,
                                             const int* __restrict__ csr_dst,
                                             float* __restrict__ agg, int N) {
    int lane = threadIdx.x & 63;
    int node = blockIdx.x * 4 + (threadIdx.x >> 6);
    if (node >= N) return;
    int s0 = off_dst[node], s1 = off_dst[node + 1];
    float acc = 0.f;
    for (int base = s0; base < s1; base += 64) {
        int idx = (base + lane < s1) ? csr_dst[base + lane] : 0;
        int cnt = min(64, s1 - base);
        for (int j = 0; j < cnt; ++j) {
            int m = __shfl(idx, j);
            acc += X[(size_t)m * NHID + lane];
        }
    }
    int deg = s1 - s0;
    agg[(size_t)node * NHID + lane] = acc / (float)max(deg, 1);
}

// ---------------------------------------------------------------------------
// K5a: X2 = relu(X·Wself + agg·Wneigh + b), thread-per-node GEMV.
// acc[64] fully in registers; weight addresses are wave-uniform on
// const __restrict__ -> compiler scalarizes to s_load (constant cache),
// FMA stream uses SGPR weight operand: no LDS, no shfl.
// Writes IN-PLACE over agg (thread n reads only row n, then writes row n).
// ---------------------------------------------------------------------------
__global__ __launch_bounds__(256) void k_phaseA(const float* __restrict__ X,
                                                const float* __restrict__ agg,
                                                const float* __restrict__ Ws,
                                                const float* __restrict__ Wn,
                                                const float* __restrict__ bconv,
                                                float* __restrict__ X2, int N) {
    int n = blockIdx.x * blockDim.x + threadIdx.x;
    if (n >= N) return;
    float acc[NHID];
    #pragma unroll
    for (int c = 0; c < NHID; ++c) acc[c] = bconv[c];
    const float4* Xv = (const float4*)(X + (size_t)n * NHID);
    const float4* Gv = (const float4*)(agg + (size_t)n * NHID);
    for (int q = 0; q < 16; ++q) {          // 4 k's per iteration
        float4 xq = Xv[q];
        float4 gq = Gv[q];
        const float xs[4] = {xq.x, xq.y, xq.z, xq.w};
        const float gs[4] = {gq.x, gq.y, gq.z, gq.w};
        #pragma unroll
        for (int j = 0; j < 4; ++j) {
            int k = q * 4 + j;
            #pragma unroll
            for (int c = 0; c < NHID; ++c) {
                acc[c] += xs[j] * Ws[k * NHID + c];
                acc[c] += gs[j] * Wn[k * NHID + c];
            }
        }
    }
    float* out = X2 + (size_t)n * NHID;
    #pragma unroll
    for (int c = 0; c < NHID; ++c) out[c] = fmaxf(acc[c], 0.f);
}

// ---------------------------------------------------------------------------
// K5b: a = X2·A + Qb ; b = X2·B as two sequential acc[64] passes.
// A[f][h*16+d] = Qw[h*2048 + f*16 + d]; B[f][h*16+d] = Qw[h*2048 + (64+f)*16 + d].
// Same uniform-weight / register-acc structure as K5a.
// ---------------------------------------------------------------------------
__global__ __launch_bounds__(256) void k_phaseB(const float* __restrict__ X2,
                                                const float* __restrict__ Qw,
                                                const float* __restrict__ Qb,
                                                float* __restrict__ aOut,
                                                float* __restrict__ bOut, int N) {
    int n = blockIdx.x * blockDim.x + threadIdx.x;
    if (n >= N) return;
    const float4* Xv = (const float4*)(X2 + (size_t)n * NHID);
    float acc[NHID];

    // pass 1: a
    #pragma unroll
    for (int c = 0; c < NHID; ++c) acc[c] = Qb[c];
    for (int q = 0; q < 16; ++q) {
        float4 xq = Xv[q];
        const float xs[4] = {xq.x, xq.y, xq.z, xq.w};
        #pragma unroll
        for (int j = 0; j < 4; ++j) {
            int f = q * 4 + j;
            #pragma unroll
            for (int c = 0; c < NHID; ++c)
                acc[c] += xs[j] * Qw[(c >> 4) * 2048 + f * 16 + (c & 15)];
        }
    }
    float* oa = aOut + (size_t)n * NHID;
    #pragma unroll
    for (int c = 0; c < NHID; ++c) oa[c] = acc[c];

    // pass 2: b
    #pragma unroll
    for (int c = 0; c < NHID; ++c) acc[c] = 0.f;
    for (int q = 0; q < 16; ++q) {
        float4 xq = Xv[q];
        const float xs[4] = {xq.x, xq.y, xq.z, xq.w};
        #pragma unroll
        for (int j = 0; j < 4; ++j) {
            int f = q * 4 + j;
            #pragma unroll
            for (int c = 0; c < NHID; ++c)
                acc[c] += xs[j] * Qw[(c >> 4) * 2048 + (64 + f) * 16 + (c & 15)];
        }
    }
    float* ob = bOut + (size_t)n * NHID;
    #pragma unroll
    for (int c = 0; c < NHID; ++c) ob[c] = acc[c];
}

// ---------------------------------------------------------------------------
// K6: gg[n,:] = tanh(mean over out-edges of (a[n,:] + b[dst,:])^2)
// ---------------------------------------------------------------------------
__global__ __launch_bounds__(256) void k_final(const float* __restrict__ aF,
                                               const float* __restrict__ bF,
                                               const int* __restrict__ off_src,
                                               const int* __restrict__ csr_src,
                                               float* __restrict__ out, int N) {
    int lane = threadIdx.x & 63;
    int node = blockIdx.x * 4 + (threadIdx.x >> 6);
    if (node >= N) return;
    int s0 = off_src[node], s1 = off_src[node + 1];
    float av = aF[(size_t)node * NHID + lane];
    float acc = 0.f;
    for (int base = s0; base < s1; base += 64) {
        int idx = (base + lane < s1) ? csr_src[base + lane] : 0;
        int cnt = min(64, s1 - base);
        for (int j = 0; j < cnt; ++j) {
            int m = __shfl(idx, j);
            float t = av + bF[(size_t)m * NHID + lane];
            acc += t * t;   // P = 2.0 -> |.|^2 == square
        }
    }
    int deg = s1 - s0;
    out[(size_t)node * NHID + lane] = tanhf(acc / (float)max(deg, 1));
}

// ---------------------------------------------------------------------------
extern "C" void kernel_launch(void* const* d_in, const int* in_sizes, int n_in,
                              void* d_out, int out_size, void* d_ws, size_t ws_size,
                              hipStream_t stream) {
    const float* X      = (const float*)d_in[0];
    const int*   ei     = (const int*)d_in[1];
    const float* Wself  = (const float*)d_in[2];
    const float* Wneigh = (const float*)d_in[3];
    const float* bconv  = (const float*)d_in[4];
    const float* Qw     = (const float*)d_in[5];
    const float* Qb     = (const float*)d_in[6];

    int N = in_sizes[0] / NHID;
    int E = in_sizes[1] / 2;
    const int* src = ei;        // edge_index[0]
    const int* dst = ei + E;    // edge_index[1]

    // workspace carve-out (~105 MB total)
    char* ws = (char*)d_ws;
    size_t pos = 0;
    auto alloc = [&](size_t bytes) -> void* {
        pos = (pos + 255) & ~(size_t)255;
        void* p = ws + pos;
        pos += bytes;
        return p;
    };
    float* aggF    = (float*)alloc((size_t)N * NHID * 4);   // agg, then X2 in-place
    float* aF      = (float*)alloc((size_t)N * NHID * 4);
    float* bF      = (float*)alloc((size_t)N * NHID * 4);
    int*   csr_dst = (int*)alloc((size_t)E * 4);
    int*   csr_src = (int*)alloc((size_t)E * 4);
    int*   cnt     = (int*)alloc((size_t)2 * N * 4);   // [cnt_dst | cnt_src]
    int*   cnt_dst = cnt;
    int*   cnt_src = cnt + N;
    int*   off_dst = (int*)alloc((size_t)(N + 1) * 4);
    int*   off_src = (int*)alloc((size_t)(N + 1) * 4);
    int*   cur_dst = (int*)alloc((size_t)N * 4);
    int*   cur_src = (int*)alloc((size_t)N * 4);
    (void)ws_size; (void)n_in; (void)out_size;

    hipMemsetAsync(cnt, 0, (size_t)2 * N * 4, stream);

    k_hist<<<4096, 256, 0, stream>>>(src, dst, cnt_src, cnt_dst, E);
    k_scan<<<2, 1024, 0, stream>>>(cnt_dst, off_dst, cur_dst,
                                   cnt_src, off_src, cur_src, N);
    k_fill<<<4096, 256, 0, stream>>>(src, dst, cur_src, cur_dst, csr_src, csr_dst, E);
    k_agg<<<(N + 3) / 4, 256, 0, stream>>>(X, off_dst, csr_dst, aggF, N);
    k_phaseA<<<(N + 255) / 256, 256, 0, stream>>>(X, aggF, Wself, Wneigh, bconv, aggF, N);
    k_phaseB<<<(N + 255) / 256, 256, 0, stream>>>(aggF, Qw, Qb, aF, bF, N);
    k_final<<<(N + 3) / 4, 256, 0, stream>>>(aF, bF, off_src, csr_src, (float*)d_out, N);
}

// Round 3
// 651.619 us; speedup vs baseline: 3.1253x; 2.3108x over previous
//
#include <hip/hip_runtime.h>
#include <math.h>

#define NHID 64
#define NPB 256          // nodes per bucket (power of two; local id = node & 255)
#define NPB_SHIFT 8
#define MAXB 512         // supports N up to 131072
#define CAP 10240        // entries per bucket region (mean 8184 @ E=3.2M, +23 sigma)
#define CHUNK 8192       // edges per k_bucketA block

// ---------------------------------------------------------------------------
// K_A: two-level bucketing of both endpoints. One block per 8192-edge chunk.
// LDS histogram over coarse buckets -> ONE global atomic per (block,bucket)
// reserves a contiguous slice -> LDS-rank scatter of packed (payload<<8|local)
// entries. Global atomics: ~300K total (vs 6.4M before).
// ---------------------------------------------------------------------------
__global__ __launch_bounds__(256) void k_bucketA(const int* __restrict__ src,
                                                 const int* __restrict__ dst,
                                                 unsigned int* __restrict__ buf0,  // keyed by dst, payload src
                                                 unsigned int* __restrict__ buf1,  // keyed by src, payload dst
                                                 int* __restrict__ btail0,
                                                 int* __restrict__ btail1,
                                                 int E, int nB) {
    __shared__ int h0[MAXB], h1[MAXB], b0[MAXB], b1[MAXB];
    int tid = threadIdx.x;
    for (int i = tid; i < nB; i += 256) { h0[i] = 0; h1[i] = 0; }
    __syncthreads();
    int e0 = blockIdx.x * CHUNK;
    for (int i = tid; i < CHUNK; i += 256) {
        int e = e0 + i;
        if (e < E) {
            atomicAdd(&h0[dst[e] >> NPB_SHIFT], 1);
            atomicAdd(&h1[src[e] >> NPB_SHIFT], 1);
        }
    }
    __syncthreads();
    for (int i = tid; i < nB; i += 256) {
        int c0 = h0[i], c1 = h1[i];
        b0[i] = c0 ? atomicAdd(&btail0[i], c0) : 0;
        b1[i] = c1 ? atomicAdd(&btail1[i], c1) : 0;
        h0[i] = 0; h1[i] = 0;       // reuse as rank counters
    }
    __syncthreads();
    for (int i = tid; i < CHUNK; i += 256) {
        int e = e0 + i;
        if (e < E) {
            int d = dst[e], s = src[e];
            int bb = d >> NPB_SHIFT;
            int r = atomicAdd(&h0[bb], 1) + b0[bb];
            if (r < CAP)
                buf0[(size_t)bb * CAP + r] = ((unsigned)s << NPB_SHIFT) | (unsigned)(d & (NPB - 1));
            bb = s >> NPB_SHIFT;
            r = atomicAdd(&h1[bb], 1) + b1[bb];
            if (r < CAP)
                buf1[(size_t)bb * CAP + r] = ((unsigned)d << NPB_SHIFT) | (unsigned)(s & (NPB - 1));
        }
    }
}

// ---------------------------------------------------------------------------
// K_B: single-block exclusive scan of per-bucket sizes (both sides).
// Also writes off[N] = total per side.
// ---------------------------------------------------------------------------
__global__ __launch_bounds__(512) void k_bscan(const int* __restrict__ btail0,
                                               const int* __restrict__ btail1,
                                               int* __restrict__ boff0, int* __restrict__ boff1,
                                               int* __restrict__ off0, int* __restrict__ off1,
                                               int nB, int N) {
    __shared__ int sd[512];
    int tid = threadIdx.x;
    // side 0
    int v = (tid < nB) ? min(btail0[tid], CAP) : 0;
    sd[tid] = v; __syncthreads();
    for (int o = 1; o < 512; o <<= 1) {
        int t = (tid >= o) ? sd[tid - o] : 0; __syncthreads();
        sd[tid] += t; __syncthreads();
    }
    if (tid < nB) boff0[tid] = sd[tid] - v;
    if (tid == 511) off0[N] = sd[511];
    __syncthreads();
    // side 1
    v = (tid < nB) ? min(btail1[tid], CAP) : 0;
    sd[tid] = v; __syncthreads();
    for (int o = 1; o < 512; o <<= 1) {
        int t = (tid >= o) ? sd[tid - o] : 0; __syncthreads();
        sd[tid] += t; __syncthreads();
    }
    if (tid < nB) boff1[tid] = sd[tid] - v;
    if (tid == 511) off1[N] = sd[511];
}

// ---------------------------------------------------------------------------
// K_C: per (side,bucket) workgroup: LDS per-node count -> LDS scan -> emit
// off[] (coalesced; this replaces the global scan over N) -> LDS-atomic rank
// scatter into the bucket's ~25KB csr window (L2-hot). Zero global atomics.
// ---------------------------------------------------------------------------
__global__ __launch_bounds__(256) void k_bucket_csr(const unsigned int* __restrict__ buf0,
                                                    const unsigned int* __restrict__ buf1,
                                                    const int* __restrict__ btail0,
                                                    const int* __restrict__ btail1,
                                                    const int* __restrict__ boff0,
                                                    const int* __restrict__ boff1,
                                                    int* __restrict__ off0, int* __restrict__ off1,
                                                    int* __restrict__ csr0, int* __restrict__ csr1,
                                                    int N) {
    int side = blockIdx.x & 1;
    int b = blockIdx.x >> 1;
    const unsigned int* buf = (side ? buf1 : buf0) + (size_t)b * CAP;
    int cnt_b = min((side ? btail1 : btail0)[b], CAP);
    int boff  = (side ? boff1 : boff0)[b];
    int* off  = side ? off1 : off0;
    int* csr  = side ? csr1 : csr0;
    __shared__ int cnt[NPB];
    __shared__ int scn[NPB];
    __shared__ int cur[NPB];
    int tid = threadIdx.x;          // blockDim == NPB == 256
    cnt[tid] = 0;
    __syncthreads();
    for (int i = tid; i < cnt_b; i += 256)
        atomicAdd(&cnt[buf[i] & (NPB - 1)], 1);
    __syncthreads();
    int v = cnt[tid];
    scn[tid] = v; __syncthreads();
    for (int o = 1; o < 256; o <<= 1) {
        int t = (tid >= o) ? scn[tid - o] : 0; __syncthreads();
        scn[tid] += t; __syncthreads();
    }
    int base = boff + scn[tid] - v;   // exclusive
    cur[tid] = base;
    int node = (b << NPB_SHIFT) + tid;
    if (node < N) off[node] = base;
    __syncthreads();
    for (int i = tid; i < cnt_b; i += 256) {
        unsigned int u = buf[i];
        int pos = atomicAdd(&cur[u & (NPB - 1)], 1);
        csr[pos] = (int)(u >> NPB_SHIFT);
    }
}

// ---------------------------------------------------------------------------
// K4: agg[n,:] = mean over in-edges of X[src,:]. Wave-per-node gather.
// ---------------------------------------------------------------------------
__global__ __launch_bounds__(256) void k_agg(const float* __restrict__ X,
                                             const int* __restrict__ off_dst,
                                             const int* __restrict__ csr_dst,
                                             float* __restrict__ agg, int N) {
    int lane = threadIdx.x & 63;
    int node = blockIdx.x * 4 + (threadIdx.x >> 6);
    if (node >= N) return;
    int s0 = off_dst[node], s1 = off_dst[node + 1];
    float acc = 0.f;
    for (int base = s0; base < s1; base += 64) {
        int idx = (base + lane < s1) ? csr_dst[base + lane] : 0;
        int cnt = min(64, s1 - base);
        for (int j = 0; j < cnt; ++j) {
            int m = __shfl(idx, j);
            acc += X[(size_t)m * NHID + lane];
        }
    }
    int deg = s1 - s0;
    agg[(size_t)node * NHID + lane] = acc / (float)max(deg, 1);
}

// ---------------------------------------------------------------------------
// K5a: X2 = relu(X·Wself + agg·Wneigh + b), thread-per-node GEMV,
// wave-uniform weight reads (scalarized), acc[64] in registers.
// Writes in-place over agg.
// ---------------------------------------------------------------------------
__global__ __launch_bounds__(256) void k_phaseA(const float* __restrict__ X,
                                                const float* __restrict__ agg,
                                                const float* __restrict__ Ws,
                                                const float* __restrict__ Wn,
                                                const float* __restrict__ bconv,
                                                float* __restrict__ X2, int N) {
    int n = blockIdx.x * blockDim.x + threadIdx.x;
    if (n >= N) return;
    float acc[NHID];
    #pragma unroll
    for (int c = 0; c < NHID; ++c) acc[c] = bconv[c];
    const float4* Xv = (const float4*)(X + (size_t)n * NHID);
    const float4* Gv = (const float4*)(agg + (size_t)n * NHID);
    for (int q = 0; q < 16; ++q) {
        float4 xq = Xv[q];
        float4 gq = Gv[q];
        const float xs[4] = {xq.x, xq.y, xq.z, xq.w};
        const float gs[4] = {gq.x, gq.y, gq.z, gq.w};
        #pragma unroll
        for (int j = 0; j < 4; ++j) {
            int k = q * 4 + j;
            #pragma unroll
            for (int c = 0; c < NHID; ++c) {
                acc[c] += xs[j] * Ws[k * NHID + c];
                acc[c] += gs[j] * Wn[k * NHID + c];
            }
        }
    }
    float* out = X2 + (size_t)n * NHID;
    #pragma unroll
    for (int c = 0; c < NHID; ++c) out[c] = fmaxf(acc[c], 0.f);
}

// ---------------------------------------------------------------------------
// K5b: a = X2·A + Qb ; b = X2·B (A/B = top/bottom halves of Qw).
// ---------------------------------------------------------------------------
__global__ __launch_bounds__(256) void k_phaseB(const float* __restrict__ X2,
                                                const float* __restrict__ Qw,
                                                const float* __restrict__ Qb,
                                                float* __restrict__ aOut,
                                                float* __restrict__ bOut, int N) {
    int n = blockIdx.x * blockDim.x + threadIdx.x;
    if (n >= N) return;
    const float4* Xv = (const float4*)(X2 + (size_t)n * NHID);
    float acc[NHID];

    #pragma unroll
    for (int c = 0; c < NHID; ++c) acc[c] = Qb[c];
    for (int q = 0; q < 16; ++q) {
        float4 xq = Xv[q];
        const float xs[4] = {xq.x, xq.y, xq.z, xq.w};
        #pragma unroll
        for (int j = 0; j < 4; ++j) {
            int f = q * 4 + j;
            #pragma unroll
            for (int c = 0; c < NHID; ++c)
                acc[c] += xs[j] * Qw[(c >> 4) * 2048 + f * 16 + (c & 15)];
        }
    }
    float* oa = aOut + (size_t)n * NHID;
    #pragma unroll
    for (int c = 0; c < NHID; ++c) oa[c] = acc[c];

    #pragma unroll
    for (int c = 0; c < NHID; ++c) acc[c] = 0.f;
    for (int q = 0; q < 16; ++q) {
        float4 xq = Xv[q];
        const float xs[4] = {xq.x, xq.y, xq.z, xq.w};
        #pragma unroll
        for (int j = 0; j < 4; ++j) {
            int f = q * 4 + j;
            #pragma unroll
            for (int c = 0; c < NHID; ++c)
                acc[c] += xs[j] * Qw[(c >> 4) * 2048 + (64 + f) * 16 + (c & 15)];
        }
    }
    float* ob = bOut + (size_t)n * NHID;
    #pragma unroll
    for (int c = 0; c < NHID; ++c) ob[c] = acc[c];
}

// ---------------------------------------------------------------------------
// K6: gg[n,:] = tanh(mean over out-edges of (a[n,:] + b[dst,:])^2)
// ---------------------------------------------------------------------------
__global__ __launch_bounds__(256) void k_final(const float* __restrict__ aF,
                                               const float* __restrict__ bF,
                                               const int* __restrict__ off_src,
                                               const int* __restrict__ csr_src,
                                               float* __restrict__ out, int N) {
    int lane = threadIdx.x & 63;
    int node = blockIdx.x * 4 + (threadIdx.x >> 6);
    if (node >= N) return;
    int s0 = off_src[node], s1 = off_src[node + 1];
    float av = aF[(size_t)node * NHID + lane];
    float acc = 0.f;
    for (int base = s0; base < s1; base += 64) {
        int idx = (base + lane < s1) ? csr_src[base + lane] : 0;
        int cnt = min(64, s1 - base);
        for (int j = 0; j < cnt; ++j) {
            int m = __shfl(idx, j);
            float t = av + bF[(size_t)m * NHID + lane];
            acc += t * t;   // P = 2.0 -> |.|^2 == square
        }
    }
    int deg = s1 - s0;
    out[(size_t)node * NHID + lane] = tanhf(acc / (float)max(deg, 1));
}

// ---------------------------------------------------------------------------
extern "C" void kernel_launch(void* const* d_in, const int* in_sizes, int n_in,
                              void* d_out, int out_size, void* d_ws, size_t ws_size,
                              hipStream_t stream) {
    const float* X      = (const float*)d_in[0];
    const int*   ei     = (const int*)d_in[1];
    const float* Wself  = (const float*)d_in[2];
    const float* Wneigh = (const float*)d_in[3];
    const float* bconv  = (const float*)d_in[4];
    const float* Qw     = (const float*)d_in[5];
    const float* Qb     = (const float*)d_in[6];

    int N = in_sizes[0] / NHID;
    int E = in_sizes[1] / 2;
    const int* src = ei;        // edge_index[0]
    const int* dst = ei + E;    // edge_index[1]
    int nB = (N + NPB - 1) >> NPB_SHIFT;           // 391 for N=100K
    int nChunks = (E + CHUNK - 1) / CHUNK;         // 391 for E=3.2M

    // ---- workspace layout (~103 MB) ----
    // [0, 77MB): bucket buffers during CSR build (2 x 21MB), then aggF/aF/bF.
    char* ws = (char*)d_ws;
    size_t bufBytes = (size_t)MAXB * CAP * 4;      // 21.0 MB per side
    unsigned int* buf0 = (unsigned int*)(ws);
    unsigned int* buf1 = (unsigned int*)(ws + bufBytes);
    float* aggF = (float*)(ws);                                   // after build
    float* aF   = (float*)(ws + (size_t)N * NHID * 4);
    float* bF   = (float*)(ws + (size_t)2 * N * NHID * 4);
    size_t pos = (size_t)3 * N * NHID * 4;
    if (pos < 2 * bufBytes) pos = 2 * bufBytes;
    pos = (pos + 255) & ~(size_t)255;
    auto alloc = [&](size_t bytes) -> void* {
        void* p = ws + pos;
        pos = (pos + bytes + 255) & ~(size_t)255;
        return p;
    };
    int* csr0   = (int*)alloc((size_t)E * 4);      // by dst
    int* csr1   = (int*)alloc((size_t)E * 4);      // by src
    int* off0   = (int*)alloc((size_t)(N + 1) * 4);
    int* off1   = (int*)alloc((size_t)(N + 1) * 4);
    int* btail0 = (int*)alloc((size_t)MAXB * 4);
    int* btail1 = (int*)alloc((size_t)MAXB * 4);
    int* boff0  = (int*)alloc((size_t)MAXB * 4);
    int* boff1  = (int*)alloc((size_t)MAXB * 4);
    (void)ws_size; (void)n_in; (void)out_size;

    hipMemsetAsync(btail0, 0, (size_t)2 * MAXB * 4, stream);   // btail0+btail1 contiguous

    k_bucketA<<<nChunks, 256, 0, stream>>>(src, dst, buf0, buf1, btail0, btail1, E, nB);
    k_bscan<<<1, 512, 0, stream>>>(btail0, btail1, boff0, boff1, off0, off1, nB, N);
    k_bucket_csr<<<nB * 2, 256, 0, stream>>>(buf0, buf1, btail0, btail1,
                                             boff0, boff1, off0, off1, csr0, csr1, N);
    k_agg<<<(N + 3) / 4, 256, 0, stream>>>(X, off0, csr0, aggF, N);
    k_phaseA<<<(N + 255) / 256, 256, 0, stream>>>(X, aggF, Wself, Wneigh, bconv, aggF, N);
    k_phaseB<<<(N + 255) / 256, 256, 0, stream>>>(aggF, Qw, Qb, aF, bF, N);
    k_final<<<(N + 3) / 4, 256, 0, stream>>>(aF, bF, off1, csr1, (float*)d_out, N);
}

// Round 4
// 489.640 us; speedup vs baseline: 4.1591x; 1.3308x over previous
//
#include <hip/hip_runtime.h>
#include <math.h>

#define NHID 64
#define NPB 256          // nodes per bucket (power of two; local id = node & 255)
#define NPB_SHIFT 8
#define MAXB 512         // supports N up to 131072
#define CAP 10240        // entries per bucket region (mean 8184 @ E=3.2M, +23 sigma)
#define CHUNK 8192       // edges per k_bucketA block

// ---------------------------------------------------------------------------
// K_A: two-level bucketing of both endpoints. One block per 8192-edge chunk.
// LDS histogram over coarse buckets -> ONE global atomic per (block,bucket)
// reserves a contiguous slice -> LDS-rank scatter of packed (payload<<8|local)
// entries. Global atomics: ~300K total.
// ---------------------------------------------------------------------------
__global__ __launch_bounds__(256) void k_bucketA(const int* __restrict__ src,
                                                 const int* __restrict__ dst,
                                                 unsigned int* __restrict__ buf0,  // keyed by dst, payload src
                                                 unsigned int* __restrict__ buf1,  // keyed by src, payload dst
                                                 int* __restrict__ btail0,
                                                 int* __restrict__ btail1,
                                                 int E, int nB) {
    __shared__ int h0[MAXB], h1[MAXB], b0[MAXB], b1[MAXB];
    int tid = threadIdx.x;
    for (int i = tid; i < nB; i += 256) { h0[i] = 0; h1[i] = 0; }
    __syncthreads();
    int e0 = blockIdx.x * CHUNK;
    for (int i = tid; i < CHUNK; i += 256) {
        int e = e0 + i;
        if (e < E) {
            atomicAdd(&h0[dst[e] >> NPB_SHIFT], 1);
            atomicAdd(&h1[src[e] >> NPB_SHIFT], 1);
        }
    }
    __syncthreads();
    for (int i = tid; i < nB; i += 256) {
        int c0 = h0[i], c1 = h1[i];
        b0[i] = c0 ? atomicAdd(&btail0[i], c0) : 0;
        b1[i] = c1 ? atomicAdd(&btail1[i], c1) : 0;
        h0[i] = 0; h1[i] = 0;       // reuse as rank counters
    }
    __syncthreads();
    for (int i = tid; i < CHUNK; i += 256) {
        int e = e0 + i;
        if (e < E) {
            int d = dst[e], s = src[e];
            int bb = d >> NPB_SHIFT;
            int r = atomicAdd(&h0[bb], 1) + b0[bb];
            if (r < CAP)
                buf0[(size_t)bb * CAP + r] = ((unsigned)s << NPB_SHIFT) | (unsigned)(d & (NPB - 1));
            bb = s >> NPB_SHIFT;
            r = atomicAdd(&h1[bb], 1) + b1[bb];
            if (r < CAP)
                buf1[(size_t)bb * CAP + r] = ((unsigned)d << NPB_SHIFT) | (unsigned)(s & (NPB - 1));
        }
    }
}

// ---------------------------------------------------------------------------
// K_B: single-block exclusive scan of per-bucket sizes (both sides).
// ---------------------------------------------------------------------------
__global__ __launch_bounds__(512) void k_bscan(const int* __restrict__ btail0,
                                               const int* __restrict__ btail1,
                                               int* __restrict__ boff0, int* __restrict__ boff1,
                                               int* __restrict__ off0, int* __restrict__ off1,
                                               int nB, int N) {
    __shared__ int sd[512];
    int tid = threadIdx.x;
    int v = (tid < nB) ? min(btail0[tid], CAP) : 0;
    sd[tid] = v; __syncthreads();
    for (int o = 1; o < 512; o <<= 1) {
        int t = (tid >= o) ? sd[tid - o] : 0; __syncthreads();
        sd[tid] += t; __syncthreads();
    }
    if (tid < nB) boff0[tid] = sd[tid] - v;
    if (tid == 511) off0[N] = sd[511];
    __syncthreads();
    v = (tid < nB) ? min(btail1[tid], CAP) : 0;
    sd[tid] = v; __syncthreads();
    for (int o = 1; o < 512; o <<= 1) {
        int t = (tid >= o) ? sd[tid - o] : 0; __syncthreads();
        sd[tid] += t; __syncthreads();
    }
    if (tid < nB) boff1[tid] = sd[tid] - v;
    if (tid == 511) off1[N] = sd[511];
}

// ---------------------------------------------------------------------------
// K_C: per (side,bucket) workgroup: LDS count -> LDS scan -> emit off[] ->
// LDS-atomic rank scatter into the bucket's csr window. Zero global atomics.
// ---------------------------------------------------------------------------
__global__ __launch_bounds__(256) void k_bucket_csr(const unsigned int* __restrict__ buf0,
                                                    const unsigned int* __restrict__ buf1,
                                                    const int* __restrict__ btail0,
                                                    const int* __restrict__ btail1,
                                                    const int* __restrict__ boff0,
                                                    const int* __restrict__ boff1,
                                                    int* __restrict__ off0, int* __restrict__ off1,
                                                    int* __restrict__ csr0, int* __restrict__ csr1,
                                                    int N) {
    int side = blockIdx.x & 1;
    int b = blockIdx.x >> 1;
    const unsigned int* buf = (side ? buf1 : buf0) + (size_t)b * CAP;
    int cnt_b = min((side ? btail1 : btail0)[b], CAP);
    int boff  = (side ? boff1 : boff0)[b];
    int* off  = side ? off1 : off0;
    int* csr  = side ? csr1 : csr0;
    __shared__ int cnt[NPB];
    __shared__ int scn[NPB];
    __shared__ int cur[NPB];
    int tid = threadIdx.x;          // blockDim == NPB == 256
    cnt[tid] = 0;
    __syncthreads();
    for (int i = tid; i < cnt_b; i += 256)
        atomicAdd(&cnt[buf[i] & (NPB - 1)], 1);
    __syncthreads();
    int v = cnt[tid];
    scn[tid] = v; __syncthreads();
    for (int o = 1; o < 256; o <<= 1) {
        int t = (tid >= o) ? scn[tid - o] : 0; __syncthreads();
        scn[tid] += t; __syncthreads();
    }
    int base = boff + scn[tid] - v;   // exclusive
    cur[tid] = base;
    int node = (b << NPB_SHIFT) + tid;
    if (node < N) off[node] = base;
    __syncthreads();
    for (int i = tid; i < cnt_b; i += 256) {
        unsigned int u = buf[i];
        int pos = atomicAdd(&cur[u & (NPB - 1)], 1);
        csr[pos] = (int)(u >> NPB_SHIFT);
    }
}

// ---------------------------------------------------------------------------
// K4: agg[n,:] = mean over in-edges of X[src,:].
// Wave = 4 row-groups x 16 float4-columns: one dwordx4 load covers 4 edges'
// full rows; 2 loads (8 edges) in flight per wave for MLP. Tail slots masked
// by 0/1 multiplier (clamped to row 0, L1-hot). Cross-group shfl_xor reduce.
// ---------------------------------------------------------------------------
__global__ __launch_bounds__(256) void k_agg(const float* __restrict__ X,
                                             const int* __restrict__ off_dst,
                                             const int* __restrict__ csr_dst,
                                             float* __restrict__ agg, int N) {
    int lane = threadIdx.x & 63;
    int node = blockIdx.x * 4 + (threadIdx.x >> 6);
    if (node >= N) return;
    int grp = lane >> 4, col = lane & 15;
    const float4* Xv = (const float4*)X;
    int s0 = off_dst[node], s1 = off_dst[node + 1];
    float4 acc = make_float4(0.f, 0.f, 0.f, 0.f);
    for (int base = s0; base < s1; base += 64) {
        int cnt = min(64, s1 - base);
        int idx = (base + lane < s1) ? csr_dst[base + lane] : 0;
        for (int j = 0; j < cnt; j += 8) {
            int q0 = j + grp, q1 = j + 4 + grp;
            int m0 = __shfl(idx, q0);
            int m1 = __shfl(idx, q1);
            float f0 = (q0 < cnt) ? 1.f : 0.f;
            float f1 = (q1 < cnt) ? 1.f : 0.f;
            if (q0 >= cnt) m0 = 0;
            if (q1 >= cnt) m1 = 0;
            float4 x0 = Xv[(size_t)m0 * 16 + col];
            float4 x1 = Xv[(size_t)m1 * 16 + col];
            acc.x += f0 * x0.x; acc.y += f0 * x0.y; acc.z += f0 * x0.z; acc.w += f0 * x0.w;
            acc.x += f1 * x1.x; acc.y += f1 * x1.y; acc.z += f1 * x1.z; acc.w += f1 * x1.w;
        }
    }
    acc.x += __shfl_xor(acc.x, 16); acc.y += __shfl_xor(acc.y, 16);
    acc.z += __shfl_xor(acc.z, 16); acc.w += __shfl_xor(acc.w, 16);
    acc.x += __shfl_xor(acc.x, 32); acc.y += __shfl_xor(acc.y, 32);
    acc.z += __shfl_xor(acc.z, 32); acc.w += __shfl_xor(acc.w, 32);
    if (grp == 0) {
        int deg = s1 - s0;
        float inv = 1.f / (float)max(deg, 1);
        float4 r = make_float4(acc.x * inv, acc.y * inv, acc.z * inv, acc.w * inv);
        ((float4*)agg)[(size_t)node * 16 + col] = r;
    }
}

// ---------------------------------------------------------------------------
// K5a: X2 = relu(X·Wself + agg·Wneigh + b), thread-per-node GEMV,
// wave-uniform weight reads (scalarized), acc[64] in registers.
// Writes in-place over agg.
// ---------------------------------------------------------------------------
__global__ __launch_bounds__(256) void k_phaseA(const float* __restrict__ X,
                                                const float* __restrict__ agg,
                                                const float* __restrict__ Ws,
                                                const float* __restrict__ Wn,
                                                const float* __restrict__ bconv,
                                                float* __restrict__ X2, int N) {
    int n = blockIdx.x * blockDim.x + threadIdx.x;
    if (n >= N) return;
    float acc[NHID];
    #pragma unroll
    for (int c = 0; c < NHID; ++c) acc[c] = bconv[c];
    const float4* Xv = (const float4*)(X + (size_t)n * NHID);
    const float4* Gv = (const float4*)(agg + (size_t)n * NHID);
    for (int q = 0; q < 16; ++q) {
        float4 xq = Xv[q];
        float4 gq = Gv[q];
        const float xs[4] = {xq.x, xq.y, xq.z, xq.w};
        const float gs[4] = {gq.x, gq.y, gq.z, gq.w};
        #pragma unroll
        for (int j = 0; j < 4; ++j) {
            int k = q * 4 + j;
            #pragma unroll
            for (int c = 0; c < NHID; ++c) {
                acc[c] += xs[j] * Ws[k * NHID + c];
                acc[c] += gs[j] * Wn[k * NHID + c];
            }
        }
    }
    float* out = X2 + (size_t)n * NHID;
    #pragma unroll
    for (int c = 0; c < NHID; ++c) out[c] = fmaxf(acc[c], 0.f);
}

// ---------------------------------------------------------------------------
// K5b: a = X2·A + Qb ; b = X2·B (A/B = top/bottom halves of Qw).
// ---------------------------------------------------------------------------
__global__ __launch_bounds__(256) void k_phaseB(const float* __restrict__ X2,
                                                const float* __restrict__ Qw,
                                                const float* __restrict__ Qb,
                                                float* __restrict__ aOut,
                                                float* __restrict__ bOut, int N) {
    int n = blockIdx.x * blockDim.x + threadIdx.x;
    if (n >= N) return;
    const float4* Xv = (const float4*)(X2 + (size_t)n * NHID);
    float acc[NHID];

    #pragma unroll
    for (int c = 0; c < NHID; ++c) acc[c] = Qb[c];
    for (int q = 0; q < 16; ++q) {
        float4 xq = Xv[q];
        const float xs[4] = {xq.x, xq.y, xq.z, xq.w};
        #pragma unroll
        for (int j = 0; j < 4; ++j) {
            int f = q * 4 + j;
            #pragma unroll
            for (int c = 0; c < NHID; ++c)
                acc[c] += xs[j] * Qw[(c >> 4) * 2048 + f * 16 + (c & 15)];
        }
    }
    float* oa = aOut + (size_t)n * NHID;
    #pragma unroll
    for (int c = 0; c < NHID; ++c) oa[c] = acc[c];

    #pragma unroll
    for (int c = 0; c < NHID; ++c) acc[c] = 0.f;
    for (int q = 0; q < 16; ++q) {
        float4 xq = Xv[q];
        const float xs[4] = {xq.x, xq.y, xq.z, xq.w};
        #pragma unroll
        for (int j = 0; j < 4; ++j) {
            int f = q * 4 + j;
            #pragma unroll
            for (int c = 0; c < NHID; ++c)
                acc[c] += xs[j] * Qw[(c >> 4) * 2048 + (64 + f) * 16 + (c & 15)];
        }
    }
    float* ob = bOut + (size_t)n * NHID;
    #pragma unroll
    for (int c = 0; c < NHID; ++c) ob[c] = acc[c];
}

// ---------------------------------------------------------------------------
// K6: gg[n,:] = tanh(mean over out-edges of (a[n,:] + b[dst,:])^2)
// Same 4-rows-per-load structure as K4.
// ---------------------------------------------------------------------------
__global__ __launch_bounds__(256) void k_final(const float* __restrict__ aF,
                                               const float* __restrict__ bF,
                                               const int* __restrict__ off_src,
                                               const int* __restrict__ csr_src,
                                               float* __restrict__ out, int N) {
    int lane = threadIdx.x & 63;
    int node = blockIdx.x * 4 + (threadIdx.x >> 6);
    if (node >= N) return;
    int grp = lane >> 4, col = lane & 15;
    const float4* Bv = (const float4*)bF;
    float4 av = ((const float4*)aF)[(size_t)node * 16 + col];
    int s0 = off_src[node], s1 = off_src[node + 1];
    float4 acc = make_float4(0.f, 0.f, 0.f, 0.f);
    for (int base = s0; base < s1; base += 64) {
        int cnt = min(64, s1 - base);
        int idx = (base + lane < s1) ? csr_src[base + lane] : 0;
        for (int j = 0; j < cnt; j += 8) {
            int q0 = j + grp, q1 = j + 4 + grp;
            int m0 = __shfl(idx, q0);
            int m1 = __shfl(idx, q1);
            float f0 = (q0 < cnt) ? 1.f : 0.f;
            float f1 = (q1 < cnt) ? 1.f : 0.f;
            if (q0 >= cnt) m0 = 0;
            if (q1 >= cnt) m1 = 0;
            float4 b0 = Bv[(size_t)m0 * 16 + col];
            float4 b1 = Bv[(size_t)m1 * 16 + col];
            float t;
            t = av.x + b0.x; acc.x += f0 * t * t;
            t = av.y + b0.y; acc.y += f0 * t * t;
            t = av.z + b0.z; acc.z += f0 * t * t;
            t = av.w + b0.w; acc.w += f0 * t * t;
            t = av.x + b1.x; acc.x += f1 * t * t;
            t = av.y + b1.y; acc.y += f1 * t * t;
            t = av.z + b1.z; acc.z += f1 * t * t;
            t = av.w + b1.w; acc.w += f1 * t * t;
        }
    }
    acc.x += __shfl_xor(acc.x, 16); acc.y += __shfl_xor(acc.y, 16);
    acc.z += __shfl_xor(acc.z, 16); acc.w += __shfl_xor(acc.w, 16);
    acc.x += __shfl_xor(acc.x, 32); acc.y += __shfl_xor(acc.y, 32);
    acc.z += __shfl_xor(acc.z, 32); acc.w += __shfl_xor(acc.w, 32);
    if (grp == 0) {
        int deg = s1 - s0;
        float inv = 1.f / (float)max(deg, 1);
        float4 r = make_float4(tanhf(acc.x * inv), tanhf(acc.y * inv),
                               tanhf(acc.z * inv), tanhf(acc.w * inv));
        ((float4*)out)[(size_t)node * 16 + col] = r;
    }
}

// ---------------------------------------------------------------------------
extern "C" void kernel_launch(void* const* d_in, const int* in_sizes, int n_in,
                              void* d_out, int out_size, void* d_ws, size_t ws_size,
                              hipStream_t stream) {
    const float* X      = (const float*)d_in[0];
    const int*   ei     = (const int*)d_in[1];
    const float* Wself  = (const float*)d_in[2];
    const float* Wneigh = (const float*)d_in[3];
    const float* bconv  = (const float*)d_in[4];
    const float* Qw     = (const float*)d_in[5];
    const float* Qb     = (const float*)d_in[6];

    int N = in_sizes[0] / NHID;
    int E = in_sizes[1] / 2;
    const int* src = ei;        // edge_index[0]
    const int* dst = ei + E;    // edge_index[1]
    int nB = (N + NPB - 1) >> NPB_SHIFT;           // 391 for N=100K
    int nChunks = (E + CHUNK - 1) / CHUNK;         // 391 for E=3.2M

    // ---- workspace layout (~103 MB) ----
    char* ws = (char*)d_ws;
    size_t bufBytes = (size_t)MAXB * CAP * 4;      // 21.0 MB per side
    unsigned int* buf0 = (unsigned int*)(ws);
    unsigned int* buf1 = (unsigned int*)(ws + bufBytes);
    float* aggF = (float*)(ws);                                   // after build
    float* aF   = (float*)(ws + (size_t)N * NHID * 4);
    float* bF   = (float*)(ws + (size_t)2 * N * NHID * 4);
    size_t pos = (size_t)3 * N * NHID * 4;
    if (pos < 2 * bufBytes) pos = 2 * bufBytes;
    pos = (pos + 255) & ~(size_t)255;
    auto alloc = [&](size_t bytes) -> void* {
        void* p = ws + pos;
        pos = (pos + bytes + 255) & ~(size_t)255;
        return p;
    };
    int* csr0   = (int*)alloc((size_t)E * 4);      // by dst
    int* csr1   = (int*)alloc((size_t)E * 4);      // by src
    int* off0   = (int*)alloc((size_t)(N + 1) * 4);
    int* off1   = (int*)alloc((size_t)(N + 1) * 4);
    int* btail0 = (int*)alloc((size_t)MAXB * 4);
    int* btail1 = (int*)alloc((size_t)MAXB * 4);
    int* boff0  = (int*)alloc((size_t)MAXB * 4);
    int* boff1  = (int*)alloc((size_t)MAXB * 4);
    (void)ws_size; (void)n_in; (void)out_size;

    hipMemsetAsync(btail0, 0, (size_t)2 * MAXB * 4, stream);   // btail0+btail1 contiguous

    k_bucketA<<<nChunks, 256, 0, stream>>>(src, dst, buf0, buf1, btail0, btail1, E, nB);
    k_bscan<<<1, 512, 0, stream>>>(btail0, btail1, boff0, boff1, off0, off1, nB, N);
    k_bucket_csr<<<nB * 2, 256, 0, stream>>>(buf0, buf1, btail0, btail1,
                                             boff0, boff1, off0, off1, csr0, csr1, N);
    k_agg<<<(N + 3) / 4, 256, 0, stream>>>(X, off0, csr0, aggF, N);
    k_phaseA<<<(N + 255) / 256, 256, 0, stream>>>(X, aggF, Wself, Wneigh, bconv, aggF, N);
    k_phaseB<<<(N + 255) / 256, 256, 0, stream>>>(aggF, Qw, Qb, aF, bF, N);
    k_final<<<(N + 3) / 4, 256, 0, stream>>>(aF, bF, off1, csr1, (float*)d_out, N);
}